// Round 1
// baseline (641.285 us; speedup 1.0000x reference)
//
#include <hip/hip_runtime.h>
#include <hip/hip_bf16.h>

// Problem constants
#define NN   207    // nodes
#define BB   8      // batch
#define CCH  2      // channels C
#define TT   12     // time steps
#define EE   64     // embed
#define HH   4      // attn heads
#define LLY  2      // layers
#define FFD  256    // FF dim (4*E)
#define NGH  8      // GAT heads
#define GALPHA 0.2f
#define GNEG  -9e15f

__device__ __forceinline__ float wred_max(float v) {
#pragma unroll
  for (int o = 32; o >= 1; o >>= 1) v = fmaxf(v, __shfl_xor(v, o));
  return v;
}
__device__ __forceinline__ float wred_sum(float v) {
#pragma unroll
  for (int o = 32; o >= 1; o >>= 1) v += __shfl_xor(v, o);
  return v;
}

// ---------------------------------------------------------------------------
// Kernel 1: GAT (8 heads) + conv1 fusion.
// grid = BT*NN blocks, one block per (b, t, i) output row. block = 256.
// Writes out0[b][n][t][e]  (B,N,T,E) f32 into workspace.
// ---------------------------------------------------------------------------
__global__ __launch_bounds__(256) void gat_conv1_kernel(
    const float* __restrict__ x,        // (B,C,N,T)
    const int*   __restrict__ adj,      // (B,N,N)
    const float* __restrict__ gat_W2,   // (8,4,2)
    const float* __restrict__ gat_a,    // (8,2)
    const float* __restrict__ gat_b,    // (8,2)
    const float* __restrict__ conv1_w,  // (4,64)
    const float* __restrict__ conv1_b,  // (64)
    float* __restrict__ out0)           // (B,N,T,E)
{
  const int bid = blockIdx.x;       // bt*NN + i
  const int i   = bid % NN;
  const int bt  = bid / NN;
  const int b   = bt / TT;
  const int t   = bt % TT;
  const int tid  = threadIdx.x;
  const int lane = tid & 63;
  const int wid  = tid >> 6;

  __shared__ float xs0[NN], xs1[NN];
  __shared__ float sW2[64];   // (8,4,2) flat
  __shared__ float sa[16];    // (8,2)
  __shared__ float sgb[16];   // (8,2)
  __shared__ float red[16];

  for (int n = tid; n < NN; n += 256) {
    xs0[n] = x[((b*CCH + 0)*NN + n)*TT + t];
    xs1[n] = x[((b*CCH + 1)*NN + n)*TT + t];
  }
  if (tid < 64) sW2[tid] = gat_W2[tid];
  if (tid < 16) { sa[tid] = gat_a[tid]; sgb[tid] = gat_b[tid]; }
  __syncthreads();

  const int j = tid;
  const bool act = (j < NN);
  float xr00=0.f, xr01=0.f, xr10=0.f, xr11=0.f, xj0=0.f, xj1=0.f;
  bool aok = false;
  if (act) {
    const int r0 = 2*(i*NN + j);
    const int r1 = r0 + 1;
    const int NSQ = NN*NN;
    const int row0 = (r0 < NSQ) ? (r0 / NN) : ((r0 - NSQ) % NN);
    const int row1 = (r1 < NSQ) ? (r1 / NN) : ((r1 - NSQ) % NN);
    xr00 = xs0[row0]; xr01 = xs1[row0];
    xr10 = xs0[row1]; xr11 = xs1[row1];
    xj0  = xs0[j];    xj1  = xs1[j];
    aok  = adj[(b*NN + i)*NN + j] > 0;
  }

  float acc0 = 0.f, acc1 = 0.f;
  for (int h = 0; h < NGH; ++h) {
    float ev = -INFINITY;
    if (act) {
      const float* w = sW2 + h*8;   // w[k*2 + e']
      float wx0 = xr00*w[0] + xr01*w[2] + xr10*w[4] + xr11*w[6];
      float wx1 = xr00*w[1] + xr01*w[3] + xr10*w[5] + xr11*w[7];
      wx0 = (wx0 > 0.f) ? wx0 : GALPHA*wx0;
      wx1 = (wx1 > 0.f) ? wx1 : GALPHA*wx1;
      ev = sa[h*2+0]*wx0 + sa[h*2+1]*wx1;
      if (!aok) ev = GNEG;
    }
    // block max
    float m = wred_max(ev);
    if (lane == 0) red[wid] = m;
    __syncthreads();
    m = fmaxf(fmaxf(red[0], red[1]), fmaxf(red[2], red[3]));
    __syncthreads();
    // fused denominator + 2 weighted sums
    float ex = act ? __expf(ev - m) : 0.f;
    float s0 = wred_sum(ex);
    float s1 = wred_sum(ex * xj0);
    float s2 = wred_sum(ex * xj1);
    if (lane == 0) { red[wid] = s0; red[4+wid] = s1; red[8+wid] = s2; }
    __syncthreads();
    const float den = red[0]+red[1]+red[2]+red[3];
    const float ws0 = red[4]+red[5]+red[6]+red[7];
    const float ws1 = red[8]+red[9]+red[10]+red[11];
    __syncthreads();
    acc0 += tanhf(ws0/den + sgb[h*2+0]);
    acc1 += tanhf(ws1/den + sgb[h*2+1]);
  }

  // fused conv1: out0[b,i,t,e] = x_i . w[0:2] + g . w[2:4] + b
  if (tid < EE) {
    const float g0 = acc0 * (1.f/NGH);
    const float g1 = acc1 * (1.f/NGH);
    const float xi0 = xs0[i], xi1 = xs1[i];
    float v = xi0*conv1_w[0*EE+tid] + xi1*conv1_w[1*EE+tid]
            + g0*conv1_w[2*EE+tid] + g1*conv1_w[3*EE+tid] + conv1_b[tid];
    out0[((b*NN + i)*TT + t)*EE + tid] = v;
  }
}

// ---------------------------------------------------------------------------
// Kernel 2: 2-layer transformer over T=12 tokens per (b,n) + final convs.
// grid = B*NN blocks. block = 256 (4 waves). Residual stream in LDS.
// ---------------------------------------------------------------------------
__global__ __launch_bounds__(256) void xf_final_kernel(
    const float* __restrict__ out0,     // (B,N,T,E)
    const float* __restrict__ temb,     // (288,E)
    const float* __restrict__ Wq, const float* __restrict__ Wk,
    const float* __restrict__ Wv, const float* __restrict__ Wo,   // (L,E,E)
    const float* __restrict__ bo,                                  // (L,E)
    const float* __restrict__ ln1_g, const float* __restrict__ ln1_b,
    const float* __restrict__ ln2_g, const float* __restrict__ ln2_b,
    const float* __restrict__ ff_w1, const float* __restrict__ ff_b1, // (L,E,FF), (L,FF)
    const float* __restrict__ ff_w2, const float* __restrict__ ff_b2, // (L,FF,E), (L,E)
    const float* __restrict__ lng, const float* __restrict__ lnb,     // (L,E)
    const float* __restrict__ conv2_w,  // (12,12)
    const float* __restrict__ conv2_b,  // (12)
    const float* __restrict__ conv3_w,  // (64)
    const float* __restrict__ conv3_b,  // (1)
    float* __restrict__ fout)           // (B,N,TOUT)
{
  const int bn   = blockIdx.x;          // b*NN + n
  const int tid  = threadIdx.x;
  const int lane = tid & 63;
  const int wid  = tid >> 6;

  __shared__ float s_out[TT*EE];
  __shared__ float s_te [TT*EE];
  __shared__ float s_qq [TT*EE];
  __shared__ float s_q  [TT*EE];
  __shared__ float s_k  [TT*EE];
  __shared__ float s_v  [TT*EE];
  __shared__ float s_sc [HH*TT*TT];   // 576
  __shared__ float s_ctx[TT*EE];
  __shared__ float s_x1 [TT*EE];
  __shared__ float s_ff [TT*FFD];     // 3072

  for (int o = tid; o < TT*EE; o += 256) {
    s_out[o] = out0[bn*(TT*EE) + o];
    s_te[o]  = temb[o];
  }
  __syncthreads();

  for (int l = 0; l < LLY; ++l) {
    const float* wq  = Wq    + l*EE*EE;
    const float* wk  = Wk    + l*EE*EE;
    const float* wv  = Wv    + l*EE*EE;
    const float* wo  = Wo    + l*EE*EE;
    const float* pbo = bo    + l*EE;
    const float* g1  = ln1_g + l*EE;  const float* b1 = ln1_b + l*EE;
    const float* g2  = ln2_g + l*EE;  const float* b2 = ln2_b + l*EE;
    const float* g3  = lng   + l*EE;  const float* b3 = lnb   + l*EE;
    const float* w1  = ff_w1 + l*EE*FFD;  const float* pb1 = ff_b1 + l*FFD;
    const float* w2  = ff_w2 + l*EE*FFD;  const float* pb2 = ff_b2 + l*EE;

    // qq = out + temb
    for (int o = tid; o < TT*EE; o += 256) s_qq[o] = s_out[o] + s_te[o];
    __syncthreads();

    // Q,K,V projections
    for (int o = tid; o < TT*EE; o += 256) {
      const int t = o >> 6, e = o & 63;
      const float* q = s_qq + t*EE;
      float aq = 0.f, ak = 0.f, av = 0.f;
#pragma unroll 8
      for (int k2 = 0; k2 < EE; ++k2) {
        const float qv = q[k2];
        aq += qv * wq[k2*EE + e];
        ak += qv * wk[k2*EE + e];
        av += qv * wv[k2*EE + e];
      }
      s_q[o] = aq; s_k[o] = ak; s_v[o] = av;
    }
    __syncthreads();

    // scores (h,t,s)
    for (int idx = tid; idx < HH*TT*TT; idx += 256) {
      const int h = idx / (TT*TT), r = idx % (TT*TT);
      const int t = r / TT, s = r % TT;
      const float* qp = s_q + t*EE + h*16;
      const float* kp = s_k + s*EE + h*16;
      float d = 0.f;
#pragma unroll
      for (int dd = 0; dd < 16; ++dd) d += qp[dd]*kp[dd];
      s_sc[idx] = d * 0.25f;   // 1/sqrt(16)
    }
    __syncthreads();

    // softmax per (h,t) row of 12
    if (tid < HH*TT) {
      float* row = s_sc + tid*TT;
      float m = row[0];
#pragma unroll
      for (int s = 1; s < TT; ++s) m = fmaxf(m, row[s]);
      float ex[TT]; float sum = 0.f;
#pragma unroll
      for (int s = 0; s < TT; ++s) { ex[s] = __expf(row[s] - m); sum += ex[s]; }
      const float inv = 1.f / sum;
#pragma unroll
      for (int s = 0; s < TT; ++s) row[s] = ex[s] * inv;
    }
    __syncthreads();

    // ctx = att @ V
    for (int o = tid; o < TT*EE; o += 256) {
      const int t = o >> 6, e = o & 63, h = e >> 4;
      const float* att = s_sc + h*(TT*TT) + t*TT;
      float c = 0.f;
#pragma unroll
      for (int s = 0; s < TT; ++s) c += att[s] * s_v[s*EE + e];
      s_ctx[o] = c;
    }
    __syncthreads();

    // attn_out = ctx @ Wo + bo ; +qq (pre-LN1)
    for (int o = tid; o < TT*EE; o += 256) {
      const int t = o >> 6, e = o & 63;
      const float* cp = s_ctx + t*EE;
      float v = pbo[e] + s_qq[o];
#pragma unroll 8
      for (int k2 = 0; k2 < EE; ++k2) v += cp[k2] * wo[k2*EE + e];
      s_x1[o] = v;
    }
    __syncthreads();

    // LN1 (wave per row)
    for (int t = wid; t < TT; t += 4) {
      float v = s_x1[t*EE + lane];
      const float mu = wred_sum(v) * (1.f/EE);
      const float d = v - mu;
      const float var = wred_sum(d*d) * (1.f/EE);
      s_x1[t*EE + lane] = d * rsqrtf(var + 1e-5f) * g1[lane] + b1[lane];
    }
    __syncthreads();

    // FF1 + relu
    for (int o = tid; o < TT*FFD; o += 256) {
      const int t = o >> 8, f = o & 255;
      const float* xp = s_x1 + t*EE;
      float v = pb1[f];
#pragma unroll 8
      for (int k2 = 0; k2 < EE; ++k2) v += xp[k2] * w1[k2*FFD + f];
      s_ff[o] = (v > 0.f) ? v : 0.f;
    }
    __syncthreads();

    // FF2 + residual(x1) (pre-LN2)
    for (int o = tid; o < TT*EE; o += 256) {
      const int t = o >> 6, e = o & 63;
      const float* fp = s_ff + t*FFD;
      float v = pb2[e] + s_x1[o];
#pragma unroll 8
      for (int k2 = 0; k2 < FFD; ++k2) v += fp[k2] * w2[k2*EE + e];
      s_ctx[o] = v;
    }
    __syncthreads();

    // LN2 -> blk ; out = LN3(blk + out)
    for (int t = wid; t < TT; t += 4) {
      float v = s_ctx[t*EE + lane];
      float mu = wred_sum(v) * (1.f/EE);
      float d = v - mu;
      float var = wred_sum(d*d) * (1.f/EE);
      const float blk = d * rsqrtf(var + 1e-5f) * g2[lane] + b2[lane];
      float w = blk + s_out[t*EE + lane];
      mu = wred_sum(w) * (1.f/EE);
      d = w - mu;
      var = wred_sum(d*d) * (1.f/EE);
      s_out[t*EE + lane] = d * rsqrtf(var + 1e-5f) * g3[lane] + b3[lane];
    }
    __syncthreads();
  }

  // final: fout[b,n,o] = c3b + sum_e c3w[e] * relu(c2b[o] + sum_t out[t,e]*c2w[o,t])
  float xt[TT];
#pragma unroll
  for (int t = 0; t < TT; ++t) xt[t] = s_out[t*EE + lane];
  const float c3w = conv3_w[lane];
  for (int o = wid; o < TT; o += 4) {
    float a = conv2_b[o];
#pragma unroll
    for (int t = 0; t < TT; ++t) a += xt[t] * conv2_w[o*TT + t];
    a = (a > 0.f) ? a : 0.f;
    const float s = wred_sum(a * c3w);
    if (lane == 0) fout[bn*TT + o] = s + conv3_b[0];
  }
}

// ---------------------------------------------------------------------------
extern "C" void kernel_launch(void* const* d_in, const int* in_sizes, int n_in,
                              void* d_out, int out_size, void* d_ws, size_t ws_size,
                              hipStream_t stream) {
  const float* x       = (const float*)d_in[0];
  const int*   adj     = (const int*)  d_in[1];
  const float* gat_W2  = (const float*)d_in[2];
  const float* gat_a   = (const float*)d_in[3];
  const float* gat_b   = (const float*)d_in[4];
  const float* conv1_w = (const float*)d_in[5];
  const float* conv1_b = (const float*)d_in[6];
  const float* temb    = (const float*)d_in[7];
  const float* Wq      = (const float*)d_in[8];
  const float* Wk      = (const float*)d_in[9];
  const float* Wv      = (const float*)d_in[10];
  const float* Wo      = (const float*)d_in[11];
  const float* bo      = (const float*)d_in[12];
  const float* ln1_g   = (const float*)d_in[13];
  const float* ln1_b   = (const float*)d_in[14];
  const float* ln2_g   = (const float*)d_in[15];
  const float* ln2_b   = (const float*)d_in[16];
  const float* ff_w1   = (const float*)d_in[17];
  const float* ff_b1   = (const float*)d_in[18];
  const float* ff_w2   = (const float*)d_in[19];
  const float* ff_b2   = (const float*)d_in[20];
  const float* lng     = (const float*)d_in[21];
  const float* lnb     = (const float*)d_in[22];
  const float* conv2_w = (const float*)d_in[23];
  const float* conv2_b = (const float*)d_in[24];
  const float* conv3_w = (const float*)d_in[25];
  const float* conv3_b = (const float*)d_in[26];

  float* out0 = (float*)d_ws;   // (B,N,T,E) f32 = 5.1 MB
  float* fout = (float*)d_out;  // (B,N,TOUT) f32

  gat_conv1_kernel<<<BB*TT*NN, 256, 0, stream>>>(
      x, adj, gat_W2, gat_a, gat_b, conv1_w, conv1_b, out0);

  xf_final_kernel<<<BB*NN, 256, 0, stream>>>(
      out0, temb, Wq, Wk, Wv, Wo, bo, ln1_g, ln1_b, ln2_g, ln2_b,
      ff_w1, ff_b1, ff_w2, ff_b2, lng, lnb,
      conv2_w, conv2_b, conv3_w, conv3_b, fout);
}

// Round 2
// 365.931 us; speedup vs baseline: 1.7525x; 1.7525x over previous
//
#include <hip/hip_runtime.h>
#include <hip/hip_bf16.h>

// Problem constants
#define NN   207
#define BB   8
#define TT   12
#define EE   64
#define HH   4
#define FFD  256
#define NGH  8
#define GALPHA 0.2f
#define GNEG  -9e15f

// LDS layout (float offsets)
//  A region (6144 floats) is time-shared:
//    GAT:  xs0[12][207] @ 0 (2484), xs1[12][207] @ 2484 (2484)
//    XF :  s_ff[12][256] @ 0 (3072), s_part[4][12][64] @ 3072 (3072)
//          s_sc[4][12][12] @ 3072 (576; dead before s_part is written)
#define L_A    0
#define L_XS0  (L_A)
#define L_XS1  (L_A + 2484)
#define L_FF   (L_A)
#define L_PART (L_A + 3072)
#define L_SC   (L_A + 3072)
#define L_OUT  6144
#define L_TE   (L_OUT + 768)
#define L_QQ   (L_TE  + 768)
#define L_Q    (L_QQ  + 768)
#define L_K    (L_Q   + 768)
#define L_V    (L_K   + 768)
#define L_CTX  (L_V   + 768)
#define L_X1   (L_CTX + 768)
#define L_GW   (L_X1  + 768)   // 64 W2 + 16 a + 16 b
#define L_TOT  (L_GW  + 96)    // 12480 floats = 49920 B

__device__ __forceinline__ float wred_max(float v) {
#pragma unroll
  for (int o = 32; o >= 1; o >>= 1) v = fmaxf(v, __shfl_xor(v, o));
  return v;
}
__device__ __forceinline__ float wred_sum(float v) {
#pragma unroll
  for (int o = 32; o >= 1; o >>= 1) v += __shfl_xor(v, o);
  return v;
}

// ---------------------------------------------------------------------------
// One block per (b, n). GAT(8 heads) -> conv1 -> 2 transformer layers ->
// conv2/conv3, residual stream lives in LDS throughout.
// ---------------------------------------------------------------------------
__global__ __launch_bounds__(256) void fused_gat_xf_kernel(
    const float* __restrict__ x,        // (B,2,N,T)
    const int*   __restrict__ adj,      // (B,N,N)
    const float* __restrict__ gat_W2,   // (8,4,2)
    const float* __restrict__ gat_a,    // (8,2)
    const float* __restrict__ gat_b,    // (8,2)
    const float* __restrict__ conv1_w,  // (4,64)
    const float* __restrict__ conv1_b,  // (64)
    const float* __restrict__ temb,     // (288,64)
    const float* __restrict__ Wq, const float* __restrict__ Wk,
    const float* __restrict__ Wv, const float* __restrict__ Wo,   // (2,64,64)
    const float* __restrict__ bo,                                  // (2,64)
    const float* __restrict__ ln1_g, const float* __restrict__ ln1_b,
    const float* __restrict__ ln2_g, const float* __restrict__ ln2_b,
    const float* __restrict__ ff_w1, const float* __restrict__ ff_b1, // (2,64,256),(2,256)
    const float* __restrict__ ff_w2, const float* __restrict__ ff_b2, // (2,256,64),(2,64)
    const float* __restrict__ lng, const float* __restrict__ lnb,     // (2,64)
    const float* __restrict__ conv2_w,  // (12,12)
    const float* __restrict__ conv2_b,  // (12)
    const float* __restrict__ conv3_w,  // (64)
    const float* __restrict__ conv3_b,  // (1)
    float* __restrict__ fout)           // (B,N,12)
{
  __shared__ float lds[L_TOT];
  const int bn   = blockIdx.x;
  const int b    = bn / NN;
  const int i    = bn % NN;
  const int tid  = threadIdx.x;
  const int lane = tid & 63;
  const int wid  = tid >> 6;

  // ---- stage x[b] transposed to xs[c][t][n], plus temb & GAT params ----
  const float* xb = x + b * 2 * NN * TT;
  for (int idx = tid; idx < 2 * NN * TT; idx += 256) {
    const int c = idx / (NN * TT);
    const int r = idx % (NN * TT);
    const int n = r / TT, t = r % TT;
    lds[L_XS0 + c * 2484 + t * NN + n] = xb[idx];
  }
  for (int o = tid; o < TT * EE; o += 256) lds[L_TE + o] = temb[o];
  if (tid < 64) lds[L_GW + tid] = gat_W2[tid];
  if (tid < 16) { lds[L_GW + 64 + tid] = gat_a[tid]; lds[L_GW + 80 + tid] = gat_b[tid]; }
  __syncthreads();

  // ---- GAT: wave w owns t in {w, w+4, w+8}; lanes span j (4 j's/lane) ----
  int   row0[4], row1[4];
  float aokf[4];
  bool  jv[4];
  {
    const int NSQ = NN * NN;
#pragma unroll
    for (int q = 0; q < 4; ++q) {
      const int j = lane + 64 * q;
      jv[q] = (j < NN);
      const int jj = jv[q] ? j : 0;
      const int r0 = 2 * (i * NN + jj), r1 = r0 + 1;
      row0[q] = (r0 < NSQ) ? (r0 / NN) : ((r0 - NSQ) % NN);
      row1[q] = (r1 < NSQ) ? (r1 / NN) : ((r1 - NSQ) % NN);
      aokf[q] = (jv[q] && adj[(b * NN + i) * NN + jj] > 0) ? 1.f : 0.f;
    }
  }

  float acc0[3] = {0.f, 0.f, 0.f}, acc1[3] = {0.f, 0.f, 0.f};
#pragma unroll
  for (int tk = 0; tk < 3; ++tk) {
    const int t = wid + 4 * tk;
    const float* xs0 = lds + L_XS0 + t * NN;
    const float* xs1 = lds + L_XS1 + t * NN;
    float xr00[4], xr01[4], xr10[4], xr11[4], xj0[4], xj1[4];
#pragma unroll
    for (int q = 0; q < 4; ++q) {
      const int j = jv[q] ? (lane + 64 * q) : 0;
      xr00[q] = xs0[row0[q]]; xr01[q] = xs1[row0[q]];
      xr10[q] = xs0[row1[q]]; xr11[q] = xs1[row1[q]];
      xj0[q]  = xs0[j];       xj1[q]  = xs1[j];
    }
    for (int h = 0; h < NGH; ++h) {
      const float w0 = lds[L_GW + h*8 + 0], w1_ = lds[L_GW + h*8 + 1];
      const float w2_= lds[L_GW + h*8 + 2], w3  = lds[L_GW + h*8 + 3];
      const float w4 = lds[L_GW + h*8 + 4], w5  = lds[L_GW + h*8 + 5];
      const float w6 = lds[L_GW + h*8 + 6], w7  = lds[L_GW + h*8 + 7];
      const float a0 = lds[L_GW + 64 + h*2], a1 = lds[L_GW + 64 + h*2 + 1];
      float ev[4];
#pragma unroll
      for (int q = 0; q < 4; ++q) {
        float wx0 = xr00[q]*w0 + xr01[q]*w2_ + xr10[q]*w4 + xr11[q]*w6;
        float wx1 = xr00[q]*w1_ + xr01[q]*w3 + xr10[q]*w5 + xr11[q]*w7;
        wx0 = (wx0 > 0.f) ? wx0 : GALPHA * wx0;
        wx1 = (wx1 > 0.f) ? wx1 : GALPHA * wx1;
        float e = a0 * wx0 + a1 * wx1;
        e = (aokf[q] > 0.f) ? e : GNEG;
        ev[q] = jv[q] ? e : -INFINITY;
      }
      float m = fmaxf(fmaxf(ev[0], ev[1]), fmaxf(ev[2], ev[3]));
      m = wred_max(m);
      float s0 = 0.f, s1 = 0.f, s2 = 0.f;
#pragma unroll
      for (int q = 0; q < 4; ++q) {
        const float ex = jv[q] ? __expf(ev[q] - m) : 0.f;
        s0 += ex; s1 += ex * xj0[q]; s2 += ex * xj1[q];
      }
      s0 = wred_sum(s0); s1 = wred_sum(s1); s2 = wred_sum(s2);
      const float inv = 1.f / s0;
      acc0[tk] += tanhf(s1 * inv + lds[L_GW + 80 + h*2]);
      acc1[tk] += tanhf(s2 * inv + lds[L_GW + 80 + h*2 + 1]);
    }
  }

  // ---- conv1 epilogue: s_out[t][e] ----
  {
    const float c1w0 = conv1_w[0*EE + lane], c1w1 = conv1_w[1*EE + lane];
    const float c1w2 = conv1_w[2*EE + lane], c1w3 = conv1_w[3*EE + lane];
    const float c1b  = conv1_b[lane];
#pragma unroll
    for (int tk = 0; tk < 3; ++tk) {
      const int t = wid + 4 * tk;
      const float xi0 = lds[L_XS0 + t*NN + i];
      const float xi1 = lds[L_XS1 + t*NN + i];
      const float g0 = acc0[tk] * (1.f / NGH), g1 = acc1[tk] * (1.f / NGH);
      lds[L_OUT + t*EE + lane] = xi0*c1w0 + xi1*c1w1 + g0*c1w2 + g1*c1w3 + c1b;
    }
  }
  __syncthreads();

  // ---- transformer layers ----
  for (int l = 0; l < 2; ++l) {
    const float* wq = Wq + l*4096; const float* wk = Wk + l*4096;
    const float* wv = Wv + l*4096; const float* wo = Wo + l*4096;

    // qq = out + temb
    for (int o = tid; o < 768; o += 256) lds[L_QQ + o] = lds[L_OUT + o] + lds[L_TE + o];
    __syncthreads();

    // QKV: wave 0->Q, 1->K, 2->V. Weight element loaded once per block;
    // activations via wave-uniform broadcast ds_read_b128 (4 FMA / LDS inst).
    if (wid < 3) {
      const float* wm = (wid == 0) ? wq : (wid == 1) ? wk : wv;
      float* dst = lds + ((wid == 0) ? L_Q : (wid == 1) ? L_K : L_V);
      float acc[12];
#pragma unroll
      for (int t = 0; t < 12; ++t) acc[t] = 0.f;
      for (int kb = 0; kb < 16; ++kb) {
        const float wr0 = wm[(4*kb + 0)*EE + lane];
        const float wr1 = wm[(4*kb + 1)*EE + lane];
        const float wr2 = wm[(4*kb + 2)*EE + lane];
        const float wr3 = wm[(4*kb + 3)*EE + lane];
#pragma unroll
        for (int t = 0; t < 12; ++t) {
          const float4 a = *(const float4*)&lds[L_QQ + t*EE + 4*kb];
          acc[t] += a.x*wr0 + a.y*wr1 + a.z*wr2 + a.w*wr3;
        }
      }
#pragma unroll
      for (int t = 0; t < 12; ++t) dst[t*EE + lane] = acc[t];
    }
    __syncthreads();

    // scores
    for (int idx = tid; idx < HH*TT*TT; idx += 256) {
      const int h = idx / 144, r2 = idx % 144, t = r2 / 12, s = r2 % 12;
      const float* qp = lds + L_Q + t*EE + h*16;
      const float* kp = lds + L_K + s*EE + h*16;
      float d = 0.f;
#pragma unroll
      for (int dd = 0; dd < 16; ++dd) d += qp[dd] * kp[dd];
      lds[L_SC + idx] = d * 0.25f;
    }
    __syncthreads();

    // softmax over s (48 rows)
    if (tid < 48) {
      float* row = lds + L_SC + tid * 12;
      float m = row[0];
#pragma unroll
      for (int s = 1; s < 12; ++s) m = fmaxf(m, row[s]);
      float ex[12]; float sum = 0.f;
#pragma unroll
      for (int s = 0; s < 12; ++s) { ex[s] = __expf(row[s] - m); sum += ex[s]; }
      const float inv = 1.f / sum;
#pragma unroll
      for (int s = 0; s < 12; ++s) row[s] = ex[s] * inv;
    }
    __syncthreads();

    // ctx = att @ V
    for (int o = tid; o < 768; o += 256) {
      const int t = o >> 6, e = o & 63, h = e >> 4;
      const float* att = lds + L_SC + h*144 + t*12;
      float c = 0.f;
#pragma unroll
      for (int s = 0; s < 12; ++s) c += att[s] * lds[L_V + s*EE + e];
      lds[L_CTX + o] = c;
    }
    __syncthreads();

    // Wo: 4-way K-split (wave kc, 16 k's each) -> partials
    {
      float acc[12];
#pragma unroll
      for (int t = 0; t < 12; ++t) acc[t] = 0.f;
      for (int kb = 0; kb < 4; ++kb) {
        const int k0 = wid*16 + 4*kb;
        const float wr0 = wo[(k0 + 0)*EE + lane];
        const float wr1 = wo[(k0 + 1)*EE + lane];
        const float wr2 = wo[(k0 + 2)*EE + lane];
        const float wr3 = wo[(k0 + 3)*EE + lane];
#pragma unroll
        for (int t = 0; t < 12; ++t) {
          const float4 a = *(const float4*)&lds[L_CTX + t*EE + k0];
          acc[t] += a.x*wr0 + a.y*wr1 + a.z*wr2 + a.w*wr3;
        }
      }
#pragma unroll
      for (int t = 0; t < 12; ++t) lds[L_PART + wid*768 + t*EE + lane] = acc[t];
    }
    __syncthreads();
    // combine + bo + residual(qq) -> s_x1
    for (int o = tid; o < 768; o += 256) {
      const int e = o & 63;
      lds[L_X1 + o] = lds[L_PART + o] + lds[L_PART + 768 + o]
                    + lds[L_PART + 1536 + o] + lds[L_PART + 2304 + o]
                    + bo[l*EE + e] + lds[L_QQ + o];
    }
    __syncthreads();

    // LN1 (wave per row)
    for (int t = wid; t < 12; t += 4) {
      float v = lds[L_X1 + t*EE + lane];
      const float mu = wred_sum(v) * (1.f/64);
      const float d = v - mu;
      const float var = wred_sum(d*d) * (1.f/64);
      lds[L_X1 + t*EE + lane] = d * rsqrtf(var + 1e-5f) * ln1_g[l*EE + lane] + ln1_b[l*EE + lane];
    }
    __syncthreads();

    // FF1 + relu: 256 threads own f
    {
      const float* w1 = ff_w1 + l*EE*FFD;
      float acc[12];
#pragma unroll
      for (int t = 0; t < 12; ++t) acc[t] = 0.f;
      for (int kb = 0; kb < 16; ++kb) {
        const float wr0 = w1[(4*kb + 0)*FFD + tid];
        const float wr1 = w1[(4*kb + 1)*FFD + tid];
        const float wr2 = w1[(4*kb + 2)*FFD + tid];
        const float wr3 = w1[(4*kb + 3)*FFD + tid];
#pragma unroll
        for (int t = 0; t < 12; ++t) {
          const float4 a = *(const float4*)&lds[L_X1 + t*EE + 4*kb];
          acc[t] += a.x*wr0 + a.y*wr1 + a.z*wr2 + a.w*wr3;
        }
      }
      const float b1v = ff_b1[l*FFD + tid];
#pragma unroll
      for (int t = 0; t < 12; ++t) lds[L_FF + t*FFD + tid] = fmaxf(acc[t] + b1v, 0.f);
    }
    __syncthreads();

    // FF2: 4-way K-split (wave kc, 64 k's each) -> partials
    {
      const float* w2 = ff_w2 + l*FFD*EE;
      float acc[12];
#pragma unroll
      for (int t = 0; t < 12; ++t) acc[t] = 0.f;
      for (int kb = 0; kb < 16; ++kb) {
        const int k0 = wid*64 + 4*kb;
        const float wr0 = w2[(k0 + 0)*EE + lane];
        const float wr1 = w2[(k0 + 1)*EE + lane];
        const float wr2 = w2[(k0 + 2)*EE + lane];
        const float wr3 = w2[(k0 + 3)*EE + lane];
#pragma unroll
        for (int t = 0; t < 12; ++t) {
          const float4 a = *(const float4*)&lds[L_FF + t*FFD + k0];
          acc[t] += a.x*wr0 + a.y*wr1 + a.z*wr2 + a.w*wr3;
        }
      }
#pragma unroll
      for (int t = 0; t < 12; ++t) lds[L_PART + wid*768 + t*EE + lane] = acc[t];
    }
    __syncthreads();
    // combine + b2 + residual(x1) -> s_ctx (pre-LN2)
    for (int o = tid; o < 768; o += 256) {
      const int e = o & 63;
      lds[L_CTX + o] = lds[L_PART + o] + lds[L_PART + 768 + o]
                     + lds[L_PART + 1536 + o] + lds[L_PART + 2304 + o]
                     + ff_b2[l*EE + e] + lds[L_X1 + o];
    }
    __syncthreads();

    // LN2 -> blk ; out = LN3(blk + out)
    for (int t = wid; t < 12; t += 4) {
      float v = lds[L_CTX + t*EE + lane];
      float mu = wred_sum(v) * (1.f/64);
      float d = v - mu;
      float var = wred_sum(d*d) * (1.f/64);
      const float blk = d * rsqrtf(var + 1e-5f) * ln2_g[l*EE + lane] + ln2_b[l*EE + lane];
      float w = blk + lds[L_OUT + t*EE + lane];
      mu = wred_sum(w) * (1.f/64);
      d = w - mu;
      var = wred_sum(d*d) * (1.f/64);
      lds[L_OUT + t*EE + lane] = d * rsqrtf(var + 1e-5f) * lng[l*EE + lane] + lnb[l*EE + lane];
    }
    __syncthreads();
  }

  // ---- final conv2 (time mix) + relu + conv3 (embed contraction) ----
  float xt[12];
#pragma unroll
  for (int t = 0; t < 12; ++t) xt[t] = lds[L_OUT + t*EE + lane];
  const float c3w = conv3_w[lane];
  for (int o = wid; o < 12; o += 4) {
    float a = conv2_b[o];
#pragma unroll
    for (int t = 0; t < 12; ++t) a += xt[t] * conv2_w[o*TT + t];
    a = fmaxf(a, 0.f);
    const float s = wred_sum(a * c3w);
    if (lane == 0) fout[bn*TT + o] = s + conv3_b[0];
  }
}

// ---------------------------------------------------------------------------
extern "C" void kernel_launch(void* const* d_in, const int* in_sizes, int n_in,
                              void* d_out, int out_size, void* d_ws, size_t ws_size,
                              hipStream_t stream) {
  const float* x       = (const float*)d_in[0];
  const int*   adj     = (const int*)  d_in[1];
  const float* gat_W2  = (const float*)d_in[2];
  const float* gat_a   = (const float*)d_in[3];
  const float* gat_b   = (const float*)d_in[4];
  const float* conv1_w = (const float*)d_in[5];
  const float* conv1_b = (const float*)d_in[6];
  const float* temb    = (const float*)d_in[7];
  const float* Wq      = (const float*)d_in[8];
  const float* Wk      = (const float*)d_in[9];
  const float* Wv      = (const float*)d_in[10];
  const float* Wo      = (const float*)d_in[11];
  const float* bo      = (const float*)d_in[12];
  const float* ln1_g   = (const float*)d_in[13];
  const float* ln1_b   = (const float*)d_in[14];
  const float* ln2_g   = (const float*)d_in[15];
  const float* ln2_b   = (const float*)d_in[16];
  const float* ff_w1   = (const float*)d_in[17];
  const float* ff_b1   = (const float*)d_in[18];
  const float* ff_w2   = (const float*)d_in[19];
  const float* ff_b2   = (const float*)d_in[20];
  const float* lng     = (const float*)d_in[21];
  const float* lnb     = (const float*)d_in[22];
  const float* conv2_w = (const float*)d_in[23];
  const float* conv2_b = (const float*)d_in[24];
  const float* conv3_w = (const float*)d_in[25];
  const float* conv3_b = (const float*)d_in[26];

  float* fout = (float*)d_out;

  fused_gat_xf_kernel<<<BB*NN, 256, 0, stream>>>(
      x, adj, gat_W2, gat_a, gat_b, conv1_w, conv1_b, temb,
      Wq, Wk, Wv, Wo, bo, ln1_g, ln1_b, ln2_g, ln2_b,
      ff_w1, ff_b1, ff_w2, ff_b2, lng, lnb,
      conv2_w, conv2_b, conv3_w, conv3_b, fout);
}